// Round 1
// baseline (644.014 us; speedup 1.0000x reference)
//
#include <hip/hip_runtime.h>
#include <cstdint>
#include <cstddef>
#include <cmath>

// ---------------------------------------------------------------------------
// GCN: 3 layers. Preprocess edges into CSR (by dst) once, then per layer:
//   h = X @ W   (SGEMM, f32 vector ALU)
//   out[v] = sum_{e:(s->v)} h[s]*dinv[s]*dinv[v] + h[v]*dinv[v]^2 + b  (CSR agg)
// Layer 3 fuses bias + log_softmax.
// ---------------------------------------------------------------------------

__global__ void hist_kernel(const int* __restrict__ dst, int* __restrict__ deg, int E) {
  int e = blockIdx.x * blockDim.x + threadIdx.x;
  if (e < E) atomicAdd(&deg[dst[e]], 1);
}

// single block, 1024 threads: exclusive scan of deg -> offsets, cursor; dinv
__global__ void scan_kernel(const int* __restrict__ deg, int* __restrict__ offsets,
                            int* __restrict__ cursor, float* __restrict__ dinv, int n) {
  __shared__ int part[1024];
  const int tid = threadIdx.x;
  const int chunk = (n + 1023) / 1024;
  const int start = min(tid * chunk, n);
  const int end   = min(start + chunk, n);
  int s = 0;
  for (int i = start; i < end; ++i) s += deg[i];
  part[tid] = s;
  __syncthreads();
  // Hillis-Steele inclusive scan over 1024 partials
  for (int off = 1; off < 1024; off <<= 1) {
    int t = (tid >= off) ? part[tid - off] : 0;
    __syncthreads();
    part[tid] += t;
    __syncthreads();
  }
  int run = (tid > 0) ? part[tid - 1] : 0;
  for (int i = start; i < end; ++i) {
    offsets[i] = run;
    cursor[i]  = run;
    dinv[i]    = rsqrtf((float)(deg[i] + 1));  // +1 self-loop; always > 0
    run += deg[i];
  }
  if (tid == 1023) offsets[n] = part[1023];
}

__global__ void fill_kernel(const int* __restrict__ src, const int* __restrict__ dst,
                            const float* __restrict__ dinv, int* __restrict__ cursor,
                            int* __restrict__ ssrc, float* __restrict__ snorm, int E) {
  int e = blockIdx.x * blockDim.x + threadIdx.x;
  if (e >= E) return;
  int s = src[e], d = dst[e];
  int p = atomicAdd(&cursor[d], 1);
  ssrc[p]  = s;
  snorm[p] = dinv[s] * dinv[d];
}

// C[M,N] = A[M,K] @ B[K,N], row-major f32. Tile 64x128, BK=16, micro 4x8.
__global__ __launch_bounds__(256) void sgemm_kernel(const float* __restrict__ A,
                                                    const float* __restrict__ B,
                                                    float* __restrict__ C,
                                                    int M, int N, int K) {
  __shared__ float As[16][68];   // [BK][BM+4], transposed A tile
  __shared__ float Bs[16][132];  // [BK][BN+4]
  const int tid  = threadIdx.x;
  const int tx   = tid & 15;   // col group: cols [tx*8, tx*8+8)
  const int ty   = tid >> 4;   // row group: rows [ty*4, ty*4+4)
  const int brow = blockIdx.x * 64;
  const int bcol = blockIdx.y * 128;

  float acc[4][8];
#pragma unroll
  for (int r = 0; r < 4; ++r)
#pragma unroll
    for (int c = 0; c < 8; ++c) acc[r][c] = 0.f;

  const int la_r = tid >> 2;        // 0..63
  const int la_c = (tid & 3) * 4;   // 0,4,8,12

  for (int k0 = 0; k0 < K; k0 += 16) {
    // A tile: each thread one float4 (rows are K-strided, K multiple of 4)
    {
      int gr = brow + la_r;
      if (gr < M) {
        const float4 v = *(const float4*)(A + (size_t)gr * K + k0 + la_c);
        As[la_c + 0][la_r] = v.x;
        As[la_c + 1][la_r] = v.y;
        As[la_c + 2][la_r] = v.z;
        As[la_c + 3][la_r] = v.w;
      } else {
        As[la_c + 0][la_r] = 0.f;
        As[la_c + 1][la_r] = 0.f;
        As[la_c + 2][la_r] = 0.f;
        As[la_c + 3][la_r] = 0.f;
      }
    }
    // B tile: 16x128, 8 scalars/thread (N may be 40: scalar + guard)
#pragma unroll
    for (int i = 0; i < 8; ++i) {
      int idx = tid * 8 + i;
      int kr  = idx >> 7;
      int col = idx & 127;
      int gc  = bcol + col;
      Bs[kr][col] = (gc < N) ? B[(size_t)(k0 + kr) * N + gc] : 0.f;
    }
    __syncthreads();
#pragma unroll
    for (int kk = 0; kk < 16; ++kk) {
      const float4 a4 = *(const float4*)&As[kk][ty * 4];
      const float4 b0 = *(const float4*)&Bs[kk][tx * 8];
      const float4 b1 = *(const float4*)&Bs[kk][tx * 8 + 4];
      const float a[4] = {a4.x, a4.y, a4.z, a4.w};
      const float b[8] = {b0.x, b0.y, b0.z, b0.w, b1.x, b1.y, b1.z, b1.w};
#pragma unroll
      for (int r = 0; r < 4; ++r)
#pragma unroll
        for (int c = 0; c < 8; ++c) acc[r][c] = fmaf(a[r], b[c], acc[r][c]);
    }
    __syncthreads();
  }
#pragma unroll
  for (int r = 0; r < 4; ++r) {
    int gr = brow + ty * 4 + r;
    if (gr >= M) continue;
#pragma unroll
    for (int c = 0; c < 8; ++c) {
      int gc = bcol + tx * 8 + c;
      if (gc < N) C[(size_t)gr * N + gc] = acc[r][c];
    }
  }
}

// Aggregation, F = blockDim.x features (128 here). One block per node.
template <bool RELU>
__global__ __launch_bounds__(128) void agg_kernel(const float* __restrict__ h,
                                                  const int* __restrict__ offsets,
                                                  const int* __restrict__ ssrc,
                                                  const float* __restrict__ snorm,
                                                  const float* __restrict__ dinv,
                                                  const float* __restrict__ bias,
                                                  float* __restrict__ out) {
  const int node = blockIdx.x;
  const int F    = blockDim.x;
  const int j    = threadIdx.x;
  const float di = dinv[node];
  float acc = h[(size_t)node * F + j] * di * di;  // self-loop
  int e = offsets[node];
  const int end = offsets[node + 1];
  for (; e < end; ++e) {
    const int   s = ssrc[e];
    const float w = snorm[e];
    acc = fmaf(h[(size_t)s * F + j], w, acc);
  }
  acc += bias[j];
  if (RELU) acc = fmaxf(acc, 0.f);
  out[(size_t)node * F + j] = acc;
}

// Final layer: F=40 classes, block of 64 (one wave). Fused bias + log_softmax.
__global__ __launch_bounds__(64) void agg_lsm_kernel(const float* __restrict__ h,
                                                     const int* __restrict__ offsets,
                                                     const int* __restrict__ ssrc,
                                                     const float* __restrict__ snorm,
                                                     const float* __restrict__ dinv,
                                                     const float* __restrict__ bias,
                                                     float* __restrict__ out, int F) {
  const int node = blockIdx.x;
  const int j    = threadIdx.x;
  const bool act = j < F;
  const float di = dinv[node];
  float acc = act ? h[(size_t)node * F + j] * di * di : 0.f;
  int e = offsets[node];
  const int end = offsets[node + 1];
  for (; e < end; ++e) {
    const int   s = ssrc[e];
    const float w = snorm[e];
    if (act) acc = fmaf(h[(size_t)s * F + j], w, acc);
  }
  if (act) acc += bias[j];
  // wave-wide log_softmax over the F active lanes
  float m = act ? acc : -INFINITY;
#pragma unroll
  for (int o = 32; o >= 1; o >>= 1) m = fmaxf(m, __shfl_xor(m, o, 64));
  float ex = act ? expf(acc - m) : 0.f;
  float ssum = ex;
#pragma unroll
  for (int o = 32; o >= 1; o >>= 1) ssum += __shfl_xor(ssum, o, 64);
  if (act) out[(size_t)node * F + j] = acc - m - logf(ssum);
}

extern "C" void kernel_launch(void* const* d_in, const int* in_sizes, int n_in,
                              void* d_out, int out_size, void* d_ws, size_t ws_size,
                              hipStream_t stream) {
  const float* x  = (const float*)d_in[0];
  const int*   ei = (const int*)d_in[1];
  const float* W1 = (const float*)d_in[2];
  const float* b1 = (const float*)d_in[3];
  const float* W2 = (const float*)d_in[4];
  const float* b2 = (const float*)d_in[5];
  const float* W3 = (const float*)d_in[6];
  const float* b3 = (const float*)d_in[7];

  const int h1   = in_sizes[3];        // 128
  const int h2   = in_sizes[5];        // 128
  const int ncls = in_sizes[7];        // 40
  const int fin  = in_sizes[2] / h1;   // 256
  const int n    = in_sizes[0] / fin;  // 50000
  const int E    = in_sizes[1] / 2;    // 800000

  const int* src = ei;
  const int* dst = ei + E;

  // workspace carve-up (256B aligned)
  char* p = (char*)d_ws;
  auto alloc = [&](size_t bytes) {
    char* r = p;
    p += (bytes + 255) & ~size_t(255);
    return r;
  };
  float* dinv  = (float*)alloc((size_t)n * 4);
  int*   deg   = (int*)alloc((size_t)n * 4);
  int*   offs  = (int*)alloc((size_t)(n + 1) * 4);
  int*   curs  = (int*)alloc((size_t)n * 4);
  int*   ssrc  = (int*)alloc((size_t)E * 4);
  float* snorm = (float*)alloc((size_t)E * 4);
  float* bufA  = (float*)alloc((size_t)n * h1 * 4);
  float* bufB  = (float*)alloc((size_t)n * h1 * 4);
  float* bufC  = bufA;  // layer-3 GEMM output reuses bufA (free by then)

  // --- CSR build (once; reused by all 3 layers) ---
  hipMemsetAsync(deg, 0, (size_t)n * 4, stream);
  hist_kernel<<<(E + 255) / 256, 256, 0, stream>>>(dst, deg, E);
  scan_kernel<<<1, 1024, 0, stream>>>(deg, offs, curs, dinv, n);
  fill_kernel<<<(E + 255) / 256, 256, 0, stream>>>(src, dst, dinv, curs, ssrc, snorm, E);

  const dim3 blk(256);
  // --- layer 1 ---
  dim3 g1((n + 63) / 64, (h1 + 127) / 128);
  sgemm_kernel<<<g1, blk, 0, stream>>>(x, W1, bufA, n, h1, fin);
  agg_kernel<true><<<n, h1, 0, stream>>>(bufA, offs, ssrc, snorm, dinv, b1, bufB);
  // --- layer 2 ---
  dim3 g2((n + 63) / 64, (h2 + 127) / 128);
  sgemm_kernel<<<g2, blk, 0, stream>>>(bufB, W2, bufA, n, h2, h1);
  agg_kernel<true><<<n, h2, 0, stream>>>(bufA, offs, ssrc, snorm, dinv, b2, bufB);
  // --- layer 3 (fused bias + log_softmax) ---
  dim3 g3((n + 63) / 64, (ncls + 127) / 128);
  sgemm_kernel<<<g3, blk, 0, stream>>>(bufB, W3, bufC, n, ncls, h2);
  agg_lsm_kernel<<<n, 64, 0, stream>>>(bufC, offs, ssrc, snorm, dinv, b3,
                                       (float*)d_out, ncls);
}

// Round 2
// 511.729 us; speedup vs baseline: 1.2585x; 1.2585x over previous
//
#include <hip/hip_runtime.h>
#include <cstdint>
#include <cstddef>
#include <cmath>

// ---------------------------------------------------------------------------
// GCN: 3 layers. Preprocess edges into CSR (by dst) once, then per layer:
//   h = X @ W   (SGEMM, f32 vector ALU)
//   out[v] = sum_{e:(s->v)} h[s]*dinv[s]*dinv[v] + h[v]*dinv[v]^2 + b  (CSR agg)
// Layer 3 fuses bias + log_softmax.
// R1: replaced 134us single-block scan with 3-kernel parallel scan.
// ---------------------------------------------------------------------------

__global__ void hist_kernel(const int* __restrict__ dst, int* __restrict__ deg, int E) {
  int e = blockIdx.x * blockDim.x + threadIdx.x;
  if (e < E) atomicAdd(&deg[dst[e]], 1);
}

// pass 1: per-block (256-wide) sums of deg
__global__ __launch_bounds__(256) void bsum_kernel(const int* __restrict__ deg,
                                                   int* __restrict__ bsum, int n) {
  __shared__ int s[256];
  const int t = threadIdx.x;
  const int i = blockIdx.x * 256 + t;
  s[t] = (i < n) ? deg[i] : 0;
  __syncthreads();
#pragma unroll
  for (int off = 128; off >= 1; off >>= 1) {
    if (t < off) s[t] += s[t + off];
    __syncthreads();
  }
  if (t == 0) bsum[blockIdx.x] = s[0];
}

// pass 2: single small block scans the <=1024 block sums -> exclusive bases
__global__ __launch_bounds__(1024) void bscan_kernel(const int* __restrict__ bsum,
                                                     int* __restrict__ bbase,
                                                     int* __restrict__ offsets,
                                                     int nb, int n) {
  __shared__ int s[1024];
  const int t = threadIdx.x;
  s[t] = (t < nb) ? bsum[t] : 0;
  __syncthreads();
  for (int off = 1; off < 1024; off <<= 1) {
    int v = (t >= off) ? s[t - off] : 0;
    __syncthreads();
    s[t] += v;
    __syncthreads();
  }
  if (t < nb) bbase[t] = (t > 0) ? s[t - 1] : 0;
  if (t == 0) offsets[n] = s[nb - 1];  // total edge count
}

// pass 3: per-block inclusive scan + base -> offsets/cursor; dinv
__global__ __launch_bounds__(256) void offs_kernel(const int* __restrict__ deg,
                                                   const int* __restrict__ bbase,
                                                   int* __restrict__ offsets,
                                                   int* __restrict__ cursor,
                                                   float* __restrict__ dinv, int n) {
  __shared__ int s[256];
  const int t = threadIdx.x;
  const int i = blockIdx.x * 256 + t;
  const int d = (i < n) ? deg[i] : 0;
  s[t] = d;
  __syncthreads();
  for (int off = 1; off < 256; off <<= 1) {
    int v = (t >= off) ? s[t - off] : 0;
    __syncthreads();
    s[t] += v;
    __syncthreads();
  }
  if (i < n) {
    const int excl = bbase[blockIdx.x] + s[t] - d;
    offsets[i] = excl;
    cursor[i]  = excl;
    dinv[i]    = rsqrtf((float)(d + 1));  // +1 self-loop; always > 0
  }
}

__global__ void fill_kernel(const int* __restrict__ src, const int* __restrict__ dst,
                            const float* __restrict__ dinv, int* __restrict__ cursor,
                            int* __restrict__ ssrc, float* __restrict__ snorm, int E) {
  int e = blockIdx.x * blockDim.x + threadIdx.x;
  if (e >= E) return;
  int s = src[e], d = dst[e];
  int p = atomicAdd(&cursor[d], 1);
  ssrc[p]  = s;
  snorm[p] = dinv[s] * dinv[d];
}

// C[M,N] = A[M,K] @ B[K,N], row-major f32. Tile 64x128, BK=16, micro 4x8.
__global__ __launch_bounds__(256) void sgemm_kernel(const float* __restrict__ A,
                                                    const float* __restrict__ B,
                                                    float* __restrict__ C,
                                                    int M, int N, int K) {
  __shared__ float As[16][68];   // [BK][BM+4], transposed A tile
  __shared__ float Bs[16][132];  // [BK][BN+4]
  const int tid  = threadIdx.x;
  const int tx   = tid & 15;   // col group: cols [tx*8, tx*8+8)
  const int ty   = tid >> 4;   // row group: rows [ty*4, ty*4+4)
  const int brow = blockIdx.x * 64;
  const int bcol = blockIdx.y * 128;

  float acc[4][8];
#pragma unroll
  for (int r = 0; r < 4; ++r)
#pragma unroll
    for (int c = 0; c < 8; ++c) acc[r][c] = 0.f;

  const int la_r = tid >> 2;        // 0..63
  const int la_c = (tid & 3) * 4;   // 0,4,8,12

  for (int k0 = 0; k0 < K; k0 += 16) {
    // A tile: each thread one float4 (rows are K-strided, K multiple of 4)
    {
      int gr = brow + la_r;
      if (gr < M) {
        const float4 v = *(const float4*)(A + (size_t)gr * K + k0 + la_c);
        As[la_c + 0][la_r] = v.x;
        As[la_c + 1][la_r] = v.y;
        As[la_c + 2][la_r] = v.z;
        As[la_c + 3][la_r] = v.w;
      } else {
        As[la_c + 0][la_r] = 0.f;
        As[la_c + 1][la_r] = 0.f;
        As[la_c + 2][la_r] = 0.f;
        As[la_c + 3][la_r] = 0.f;
      }
    }
    // B tile: 16x128, 8 scalars/thread (N may be 40: scalar + guard)
#pragma unroll
    for (int i = 0; i < 8; ++i) {
      int idx = tid * 8 + i;
      int kr  = idx >> 7;
      int col = idx & 127;
      int gc  = bcol + col;
      Bs[kr][col] = (gc < N) ? B[(size_t)(k0 + kr) * N + gc] : 0.f;
    }
    __syncthreads();
#pragma unroll
    for (int kk = 0; kk < 16; ++kk) {
      const float4 a4 = *(const float4*)&As[kk][ty * 4];
      const float4 b0 = *(const float4*)&Bs[kk][tx * 8];
      const float4 b1 = *(const float4*)&Bs[kk][tx * 8 + 4];
      const float a[4] = {a4.x, a4.y, a4.z, a4.w};
      const float b[8] = {b0.x, b0.y, b0.z, b0.w, b1.x, b1.y, b1.z, b1.w};
#pragma unroll
      for (int r = 0; r < 4; ++r)
#pragma unroll
        for (int c = 0; c < 8; ++c) acc[r][c] = fmaf(a[r], b[c], acc[r][c]);
    }
    __syncthreads();
  }
#pragma unroll
  for (int r = 0; r < 4; ++r) {
    int gr = brow + ty * 4 + r;
    if (gr >= M) continue;
#pragma unroll
    for (int c = 0; c < 8; ++c) {
      int gc = bcol + tx * 8 + c;
      if (gc < N) C[(size_t)gr * N + gc] = acc[r][c];
    }
  }
}

// Aggregation, F = blockDim.x features (128 here). One block per node.
template <bool RELU>
__global__ __launch_bounds__(128) void agg_kernel(const float* __restrict__ h,
                                                  const int* __restrict__ offsets,
                                                  const int* __restrict__ ssrc,
                                                  const float* __restrict__ snorm,
                                                  const float* __restrict__ dinv,
                                                  const float* __restrict__ bias,
                                                  float* __restrict__ out) {
  const int node = blockIdx.x;
  const int F    = blockDim.x;
  const int j    = threadIdx.x;
  const float di = dinv[node];
  float acc = h[(size_t)node * F + j] * di * di;  // self-loop
  int e = offsets[node];
  const int end = offsets[node + 1];
  for (; e < end; ++e) {
    const int   s = ssrc[e];
    const float w = snorm[e];
    acc = fmaf(h[(size_t)s * F + j], w, acc);
  }
  acc += bias[j];
  if (RELU) acc = fmaxf(acc, 0.f);
  out[(size_t)node * F + j] = acc;
}

// Final layer: F=40 classes, block of 64 (one wave). Fused bias + log_softmax.
__global__ __launch_bounds__(64) void agg_lsm_kernel(const float* __restrict__ h,
                                                     const int* __restrict__ offsets,
                                                     const int* __restrict__ ssrc,
                                                     const float* __restrict__ snorm,
                                                     const float* __restrict__ dinv,
                                                     const float* __restrict__ bias,
                                                     float* __restrict__ out, int F) {
  const int node = blockIdx.x;
  const int j    = threadIdx.x;
  const bool act = j < F;
  const float di = dinv[node];
  float acc = act ? h[(size_t)node * F + j] * di * di : 0.f;
  int e = offsets[node];
  const int end = offsets[node + 1];
  for (; e < end; ++e) {
    const int   s = ssrc[e];
    const float w = snorm[e];
    if (act) acc = fmaf(h[(size_t)s * F + j], w, acc);
  }
  if (act) acc += bias[j];
  // wave-wide log_softmax over the F active lanes
  float m = act ? acc : -INFINITY;
#pragma unroll
  for (int o = 32; o >= 1; o >>= 1) m = fmaxf(m, __shfl_xor(m, o, 64));
  float ex = act ? expf(acc - m) : 0.f;
  float ssum = ex;
#pragma unroll
  for (int o = 32; o >= 1; o >>= 1) ssum += __shfl_xor(ssum, o, 64);
  if (act) out[(size_t)node * F + j] = acc - m - logf(ssum);
}

extern "C" void kernel_launch(void* const* d_in, const int* in_sizes, int n_in,
                              void* d_out, int out_size, void* d_ws, size_t ws_size,
                              hipStream_t stream) {
  const float* x  = (const float*)d_in[0];
  const int*   ei = (const int*)d_in[1];
  const float* W1 = (const float*)d_in[2];
  const float* b1 = (const float*)d_in[3];
  const float* W2 = (const float*)d_in[4];
  const float* b2 = (const float*)d_in[5];
  const float* W3 = (const float*)d_in[6];
  const float* b3 = (const float*)d_in[7];

  const int h1   = in_sizes[3];        // 128
  const int h2   = in_sizes[5];        // 128
  const int ncls = in_sizes[7];        // 40
  const int fin  = in_sizes[2] / h1;   // 256
  const int n    = in_sizes[0] / fin;  // 50000
  const int E    = in_sizes[1] / 2;    // 800000

  const int* src = ei;
  const int* dst = ei + E;

  // workspace carve-up (256B aligned)
  char* p = (char*)d_ws;
  auto alloc = [&](size_t bytes) {
    char* r = p;
    p += (bytes + 255) & ~size_t(255);
    return r;
  };
  float* dinv  = (float*)alloc((size_t)n * 4);
  int*   deg   = (int*)alloc((size_t)n * 4);
  int*   offs  = (int*)alloc((size_t)(n + 1) * 4);
  int*   curs  = (int*)alloc((size_t)n * 4);
  int*   bsum  = (int*)alloc(1024 * 4);
  int*   bbase = (int*)alloc(1024 * 4);
  int*   ssrc  = (int*)alloc((size_t)E * 4);
  float* snorm = (float*)alloc((size_t)E * 4);
  float* bufA  = (float*)alloc((size_t)n * h1 * 4);
  float* bufB  = (float*)alloc((size_t)n * h1 * 4);
  float* bufC  = bufA;  // layer-3 GEMM output reuses bufA (free by then)

  const int nb = (n + 255) / 256;  // 196 blocks <= 1024

  // --- CSR build (once; reused by all 3 layers) ---
  hipMemsetAsync(deg, 0, (size_t)n * 4, stream);
  hist_kernel<<<(E + 255) / 256, 256, 0, stream>>>(dst, deg, E);
  bsum_kernel<<<nb, 256, 0, stream>>>(deg, bsum, n);
  bscan_kernel<<<1, 1024, 0, stream>>>(bsum, bbase, offs, nb, n);
  offs_kernel<<<nb, 256, 0, stream>>>(deg, bbase, offs, curs, dinv, n);
  fill_kernel<<<(E + 255) / 256, 256, 0, stream>>>(src, dst, dinv, curs, ssrc, snorm, E);

  const dim3 blk(256);
  // --- layer 1 ---
  dim3 g1((n + 63) / 64, (h1 + 127) / 128);
  sgemm_kernel<<<g1, blk, 0, stream>>>(x, W1, bufA, n, h1, fin);
  agg_kernel<true><<<n, h1, 0, stream>>>(bufA, offs, ssrc, snorm, dinv, b1, bufB);
  // --- layer 2 ---
  dim3 g2((n + 63) / 64, (h2 + 127) / 128);
  sgemm_kernel<<<g2, blk, 0, stream>>>(bufB, W2, bufA, n, h2, h1);
  agg_kernel<true><<<n, h2, 0, stream>>>(bufA, offs, ssrc, snorm, dinv, b2, bufB);
  // --- layer 3 (fused bias + log_softmax) ---
  dim3 g3((n + 63) / 64, (ncls + 127) / 128);
  sgemm_kernel<<<g3, blk, 0, stream>>>(bufB, W3, bufC, n, ncls, h2);
  agg_lsm_kernel<<<n, 64, 0, stream>>>(bufC, offs, ssrc, snorm, dinv, b3,
                                       (float*)d_out, ncls);
}

// Round 3
// 391.475 us; speedup vs baseline: 1.6451x; 1.3072x over previous
//
#include <hip/hip_runtime.h>
#include <cstdint>
#include <cstddef>
#include <cmath>

// ---------------------------------------------------------------------------
// GCN: 3 layers. CSR (by dst) built once, then per layer:
//   h = X @ W   (bf16 MFMA GEMM, f32 accumulate)
//   out[v] = sum_e h[s]*norm + h[v]*dinv^2 + b   (CSR agg, f32; emits bf16)
// Layer 3 fuses bias + log_softmax (f32 out).
// R1: parallel scan. R2: GEMM -> mfma_f32_16x16x32_bf16; W pre-packed into
//     fragment order; A staged in LDS with XOR swizzle; agg outputs bf16.
// ---------------------------------------------------------------------------

typedef __attribute__((ext_vector_type(8))) short short8;
typedef __attribute__((ext_vector_type(4))) float f32x4;

__device__ __forceinline__ ushort f2bf(float f) {
  union { float f; uint32_t u; } x; x.f = f;
  uint32_t r = x.u + 0x7fffu + ((x.u >> 16) & 1u);  // RNE
  return (ushort)(r >> 16);
}

// ---------------- CSR build ----------------
__global__ void hist_kernel(const int* __restrict__ dst, int* __restrict__ deg, int E) {
  int e = blockIdx.x * blockDim.x + threadIdx.x;
  if (e < E) atomicAdd(&deg[dst[e]], 1);
}

__global__ __launch_bounds__(256) void bsum_kernel(const int* __restrict__ deg,
                                                   int* __restrict__ bsum, int n) {
  __shared__ int s[256];
  const int t = threadIdx.x;
  const int i = blockIdx.x * 256 + t;
  s[t] = (i < n) ? deg[i] : 0;
  __syncthreads();
#pragma unroll
  for (int off = 128; off >= 1; off >>= 1) {
    if (t < off) s[t] += s[t + off];
    __syncthreads();
  }
  if (t == 0) bsum[blockIdx.x] = s[0];
}

__global__ __launch_bounds__(1024) void bscan_kernel(const int* __restrict__ bsum,
                                                     int* __restrict__ bbase,
                                                     int* __restrict__ offsets,
                                                     int nb, int n) {
  __shared__ int s[1024];
  const int t = threadIdx.x;
  s[t] = (t < nb) ? bsum[t] : 0;
  __syncthreads();
  for (int off = 1; off < 1024; off <<= 1) {
    int v = (t >= off) ? s[t - off] : 0;
    __syncthreads();
    s[t] += v;
    __syncthreads();
  }
  if (t < nb) bbase[t] = (t > 0) ? s[t - 1] : 0;
  if (t == 0) offsets[n] = s[nb - 1];
}

__global__ __launch_bounds__(256) void offs_kernel(const int* __restrict__ deg,
                                                   const int* __restrict__ bbase,
                                                   int* __restrict__ offsets,
                                                   int* __restrict__ cursor,
                                                   float* __restrict__ dinv, int n) {
  __shared__ int s[256];
  const int t = threadIdx.x;
  const int i = blockIdx.x * 256 + t;
  const int d = (i < n) ? deg[i] : 0;
  s[t] = d;
  __syncthreads();
  for (int off = 1; off < 256; off <<= 1) {
    int v = (t >= off) ? s[t - off] : 0;
    __syncthreads();
    s[t] += v;
    __syncthreads();
  }
  if (i < n) {
    const int excl = bbase[blockIdx.x] + s[t] - d;
    offsets[i] = excl;
    cursor[i]  = excl;
    dinv[i]    = rsqrtf((float)(d + 1));
  }
}

__global__ void fill_kernel(const int* __restrict__ src, const int* __restrict__ dst,
                            const float* __restrict__ dinv, int* __restrict__ cursor,
                            int* __restrict__ ssrc, float* __restrict__ snorm, int E) {
  int e = blockIdx.x * blockDim.x + threadIdx.x;
  if (e >= E) return;
  int s = src[e], d = dst[e];
  int p = atomicAdd(&cursor[d], 1);
  ssrc[p]  = s;
  snorm[p] = dinv[s] * dinv[d];
}

// ---------------- W pre-pack into MFMA B-fragment order ----------------
// Wp[(g*NF + nf)*64 + lane] holds 8 bf16: B[k = g*32 + (lane>>4)*8 + j][n = nf*16 + (lane&15)]
__global__ __launch_bounds__(256) void pack_w_kernel(const float* __restrict__ W,
                                                     ushort* __restrict__ Wp,
                                                     int K, int N, int NF) {
  const int idx  = blockIdx.x * blockDim.x + threadIdx.x;
  const int lane = idx & 63;
  const int nf   = (idx >> 6) % NF;
  const int g    = idx / (64 * NF);
  if (g * 32 >= K) return;
  const int n  = nf * 16 + (lane & 15);
  const int kb = g * 32 + (lane >> 4) * 8;
  ushort v[8];
#pragma unroll
  for (int j = 0; j < 8; ++j) {
    const float f = (n < N) ? W[(size_t)(kb + j) * N + n] : 0.f;
    v[j] = f2bf(f);
  }
  *(short8*)&Wp[((size_t)(g * NF + nf) * 64 + lane) * 8] = *(short8*)v;
}

// ---------------- MFMA GEMM: C[M,N] = A[M,K] @ W[K,N] ----------------
// BM=64 (4 waves x 16 rows), BK=64 staged in LDS (XOR-swizzled), B from packed global.
template <int NF, bool AF32>
__global__ __launch_bounds__(256) void mfma_gemm_kernel(const void* __restrict__ Av,
                                                        const ushort* __restrict__ Wp,
                                                        float* __restrict__ C,
                                                        int M, int N, int K) {
  __shared__ ushort Atile[64 * 64];  // 8 KB bf16, row stride 128 B (= bank period)
  const int tid  = threadIdx.x;
  const int lane = tid & 63;
  const int wave = tid >> 6;
  const int brow = blockIdx.x * 64;

  f32x4 acc[NF];
#pragma unroll
  for (int nf = 0; nf < NF; ++nf) acc[nf] = (f32x4){0.f, 0.f, 0.f, 0.f};

  const int arow = wave * 16 + (lane & 15);  // A fragment row within tile
  const int ahi  = lane >> 4;                // k-chunk selector within mfma-K
  const int row0 = tid >> 3;                 // staging: chunk row (0..31), +32 for chunk 1
  const int kc0  = tid & 7;                  // staging: k-chunk (8 bf16 = 16B)

  for (int k0 = 0; k0 < K; k0 += 64) {
    if (k0) __syncthreads();
    // stage A tile (64 rows x 64 k) with XOR swizzle kc' = kc ^ (row&7)
#pragma unroll
    for (int c = 0; c < 2; ++c) {
      const int row = row0 + c * 32;
      const int gr  = brow + row;
      short8 v = (short8){0, 0, 0, 0, 0, 0, 0, 0};
      if (gr < M) {
        if constexpr (AF32) {
          const float* A = (const float*)Av + (size_t)gr * K + k0 + kc0 * 8;
          const float4 f0 = *(const float4*)A;
          const float4 f1 = *(const float4*)(A + 4);
          v[0] = (short)f2bf(f0.x); v[1] = (short)f2bf(f0.y);
          v[2] = (short)f2bf(f0.z); v[3] = (short)f2bf(f0.w);
          v[4] = (short)f2bf(f1.x); v[5] = (short)f2bf(f1.y);
          v[6] = (short)f2bf(f1.z); v[7] = (short)f2bf(f1.w);
        } else {
          v = *(const short8*)((const ushort*)Av + (size_t)gr * K + k0 + kc0 * 8);
        }
      }
      *(short8*)&Atile[row * 64 + ((kc0 ^ (row & 7)) * 8)] = v;
    }
    __syncthreads();

    const int gbase = (k0 >> 5) * NF;  // fragment-group base for this tile
#pragma unroll
    for (int kk = 0; kk < 2; ++kk) {
      const int kc = kk * 4 + ahi;
      const short8 a =
          *(const short8*)&Atile[arow * 64 + ((kc ^ (arow & 7)) * 8)];
      const ushort* wp = Wp + ((size_t)(gbase + kk * NF) * 64 + lane) * 8;
#pragma unroll
      for (int nf = 0; nf < NF; ++nf) {
        const short8 b = *(const short8*)(wp + (size_t)nf * 64 * 8);
        acc[nf] = __builtin_amdgcn_mfma_f32_16x16x32_bf16(a, b, acc[nf], 0, 0, 0);
      }
    }
  }

  // epilogue: C/D layout col = lane&15, row = (lane>>4)*4 + r
  const int crow0 = brow + wave * 16 + (lane >> 4) * 4;
  const int ccol  = lane & 15;
#pragma unroll
  for (int nf = 0; nf < NF; ++nf) {
    const int col = nf * 16 + ccol;
    if (col < N) {
#pragma unroll
      for (int r = 0; r < 4; ++r) {
        const int row = crow0 + r;
        if (row < M) C[(size_t)row * N + col] = acc[nf][r];
      }
    }
  }
}

// ---------------- Aggregation (f32 math, bf16 out for next GEMM) ----------------
template <bool RELU>
__global__ __launch_bounds__(128) void agg_kernel(const float* __restrict__ h,
                                                  const int* __restrict__ offsets,
                                                  const int* __restrict__ ssrc,
                                                  const float* __restrict__ snorm,
                                                  const float* __restrict__ dinv,
                                                  const float* __restrict__ bias,
                                                  ushort* __restrict__ out) {
  const int node = blockIdx.x;
  const int F    = blockDim.x;
  const int j    = threadIdx.x;
  const float di = dinv[node];
  float acc = h[(size_t)node * F + j] * di * di;  // self-loop
  int e = offsets[node];
  const int end = offsets[node + 1];
  for (; e < end; ++e) {
    const int   s = ssrc[e];
    const float w = snorm[e];
    acc = fmaf(h[(size_t)s * F + j], w, acc);
  }
  acc += bias[j];
  if (RELU) acc = fmaxf(acc, 0.f);
  out[(size_t)node * F + j] = f2bf(acc);
}

// Final layer: F=40 classes, one wave per node. Fused bias + log_softmax.
__global__ __launch_bounds__(64) void agg_lsm_kernel(const float* __restrict__ h,
                                                     const int* __restrict__ offsets,
                                                     const int* __restrict__ ssrc,
                                                     const float* __restrict__ snorm,
                                                     const float* __restrict__ dinv,
                                                     const float* __restrict__ bias,
                                                     float* __restrict__ out, int F) {
  const int node = blockIdx.x;
  const int j    = threadIdx.x;
  const bool act = j < F;
  const float di = dinv[node];
  float acc = act ? h[(size_t)node * F + j] * di * di : 0.f;
  int e = offsets[node];
  const int end = offsets[node + 1];
  for (; e < end; ++e) {
    const int   s = ssrc[e];
    const float w = snorm[e];
    if (act) acc = fmaf(h[(size_t)s * F + j], w, acc);
  }
  if (act) acc += bias[j];
  float m = act ? acc : -INFINITY;
#pragma unroll
  for (int o = 32; o >= 1; o >>= 1) m = fmaxf(m, __shfl_xor(m, o, 64));
  float ex = act ? expf(acc - m) : 0.f;
  float ssum = ex;
#pragma unroll
  for (int o = 32; o >= 1; o >>= 1) ssum += __shfl_xor(ssum, o, 64);
  if (act) out[(size_t)node * F + j] = acc - m - logf(ssum);
}

extern "C" void kernel_launch(void* const* d_in, const int* in_sizes, int n_in,
                              void* d_out, int out_size, void* d_ws, size_t ws_size,
                              hipStream_t stream) {
  const float* x  = (const float*)d_in[0];
  const int*   ei = (const int*)d_in[1];
  const float* W1 = (const float*)d_in[2];
  const float* b1 = (const float*)d_in[3];
  const float* W2 = (const float*)d_in[4];
  const float* b2 = (const float*)d_in[5];
  const float* W3 = (const float*)d_in[6];
  const float* b3 = (const float*)d_in[7];

  const int h1   = in_sizes[3];        // 128
  const int h2   = in_sizes[5];        // 128
  const int ncls = in_sizes[7];        // 40
  const int fin  = in_sizes[2] / h1;   // 256
  const int n    = in_sizes[0] / fin;  // 50000
  const int E    = in_sizes[1] / 2;    // 800000

  const int* src = ei;
  const int* dst = ei + E;

  char* p = (char*)d_ws;
  auto alloc = [&](size_t bytes) {
    char* r = p;
    p += (bytes + 255) & ~size_t(255);
    return r;
  };
  float*  dinv  = (float*)alloc((size_t)n * 4);
  int*    deg   = (int*)alloc((size_t)n * 4);
  int*    offs  = (int*)alloc((size_t)(n + 1) * 4);
  int*    curs  = (int*)alloc((size_t)n * 4);
  int*    bsum  = (int*)alloc(1024 * 4);
  int*    bbase = (int*)alloc(1024 * 4);
  int*    ssrc  = (int*)alloc((size_t)E * 4);
  float*  snorm = (float*)alloc((size_t)E * 4);
  float*  bufA  = (float*)alloc((size_t)n * h1 * 4);   // GEMM out (f32)
  ushort* hb    = (ushort*)alloc((size_t)n * h1 * 2);  // agg out (bf16)
  ushort* Wp1   = (ushort*)alloc((size_t)(fin / 32) * 8 * 64 * 8 * 2);
  ushort* Wp2   = (ushort*)alloc((size_t)(h1 / 32) * 8 * 64 * 8 * 2);
  ushort* Wp3   = (ushort*)alloc((size_t)(h2 / 32) * 3 * 64 * 8 * 2);
  float*  bufC  = bufA;  // layer-3 GEMM out reuses bufA

  const int nb = (n + 255) / 256;

  // --- CSR build ---
  hipMemsetAsync(deg, 0, (size_t)n * 4, stream);
  hist_kernel<<<(E + 255) / 256, 256, 0, stream>>>(dst, deg, E);
  bsum_kernel<<<nb, 256, 0, stream>>>(deg, bsum, n);
  bscan_kernel<<<1, 1024, 0, stream>>>(bsum, bbase, offs, nb, n);
  offs_kernel<<<nb, 256, 0, stream>>>(deg, bbase, offs, curs, dinv, n);
  fill_kernel<<<(E + 255) / 256, 256, 0, stream>>>(src, dst, dinv, curs, ssrc, snorm, E);

  // --- pack weights (fragment order, bf16) ---
  {
    int t1 = (fin / 32) * 8 * 64;  // 4096
    int t2 = (h1 / 32) * 8 * 64;   // 2048
    int t3 = (h2 / 32) * 3 * 64;   // 768
    pack_w_kernel<<<(t1 + 255) / 256, 256, 0, stream>>>(W1, Wp1, fin, h1, 8);
    pack_w_kernel<<<(t2 + 255) / 256, 256, 0, stream>>>(W2, Wp2, h1, h2, 8);
    pack_w_kernel<<<(t3 + 255) / 256, 256, 0, stream>>>(W3, Wp3, h2, ncls, 3);
  }

  const int gblocks = (n + 63) / 64;  // 782

  // --- layer 1 ---
  mfma_gemm_kernel<8, true><<<gblocks, 256, 0, stream>>>(x, Wp1, bufA, n, h1, fin);
  agg_kernel<true><<<n, h1, 0, stream>>>(bufA, offs, ssrc, snorm, dinv, b1, hb);
  // --- layer 2 ---
  mfma_gemm_kernel<8, false><<<gblocks, 256, 0, stream>>>(hb, Wp2, bufA, n, h2, h1);
  agg_kernel<true><<<n, h2, 0, stream>>>(bufA, offs, ssrc, snorm, dinv, b2, hb);
  // --- layer 3 ---
  mfma_gemm_kernel<3, false><<<gblocks, 256, 0, stream>>>(hb, Wp3, bufC, n, ncls, h2);
  agg_lsm_kernel<<<n, 64, 0, stream>>>(bufC, offs, ssrc, snorm, dinv, b3,
                                       (float*)d_out, ncls);
}